// Round 1
// baseline (6376.096 us; speedup 1.0000x reference)
//
#include <hip/hip_runtime.h>
#include <cstdint>
#include <cstddef>

typedef unsigned int u32;
typedef float  f32x4  __attribute__((ext_vector_type(4)));
typedef int    i32x4  __attribute__((ext_vector_type(4)));
typedef short  bf16x8 __attribute__((ext_vector_type(8)));

#define DEV static __device__ __forceinline__

#define TT 512
#define II 128

// ---------------- workspace layout (bytes) ----------------
#define OFF_CNT_E 0u
#define OFF_CNT_G 8192u
#define OFF_HX    16384u                    // 2 groups * 2 parity * 131072
#define OFF_GX    (OFF_HX + 524288u)        // 2 * 2 * 32768
#define OFF_BE    (OFF_GX + 131072u)        // 64 panels * 18 chunks * 8192
#define OFF_BG    (OFF_BE + 9437184u)       // 16 panels * 6 chunks * 24576
#define OFF_EHF   (OFF_BG + 2359296u)       // 64*2048*4
#define OFF_GHF   (OFF_EHF + 524288u)       // 64*512*4
#define OFF_PROJ  (OFF_GHF + 131072u)
#define OFF_COMB  (OFF_PROJ + 131072u)
#define OFF_HID   (OFF_COMB + 131072u)

// ---------------- small helpers ----------------
DEV u32 f2bf(float f){ u32 u = __float_as_uint(f); return (u + 0x7FFFu + ((u >> 16) & 1u)) >> 16; }
DEV float bf2f(u32 s){ return __uint_as_float(s << 16); }

DEV i32x4 ld4_sc(const void* p){ i32x4 r; asm volatile("global_load_dwordx4 %0, %1, off sc0 sc1" : "=v"(r) : "v"(p)); return r; }
DEV i32x4 ld4(const void* p){ i32x4 r; asm volatile("global_load_dwordx4 %0, %1, off" : "=v"(r) : "v"(p)); return r; }
template<int OFF> DEV i32x4 ld4o(const void* p){ i32x4 r; asm volatile("global_load_dwordx4 %0, %1, off offset:%c2" : "=v"(r) : "v"(p), "n"(OFF)); return r; }
template<int OFF> DEV i32x4 ld4o_sc(const void* p){ i32x4 r; asm volatile("global_load_dwordx4 %0, %1, off offset:%c2 sc0 sc1" : "=v"(r) : "v"(p), "n"(OFF)); return r; }
DEV void st2_sc(void* p, u32 v){ asm volatile("global_store_short %0, %1, off sc0 sc1" :: "v"(p), "v"(v)); }

#define WAITV(n) do { asm volatile("s_waitcnt vmcnt(" #n ")" ::: "memory"); __builtin_amdgcn_sched_barrier(0); } while(0)
#define WAITV0() do { asm volatile("s_waitcnt vmcnt(0)" ::: "memory"); __builtin_amdgcn_sched_barrier(0); } while(0)

DEV void poll_ge(const u32* p, u32 tgt){
  for (int it = 0; it < (1 << 22); ++it){
    u32 v;
    asm volatile("global_load_dword %0, %1, off sc0 sc1\n\ts_waitcnt vmcnt(0)" : "=v"(v) : "v"(p) : "memory");
    if (v >= tgt) return;
    __builtin_amdgcn_s_sleep(2);
  }
}

DEV f32x4 mfma16(bf16x8 a, bf16x8 b, f32x4 c){ return __builtin_amdgcn_mfma_f32_16x16x32_bf16(a, b, c, 0, 0, 0); }
DEV bf16x8 as_bf(i32x4 v){ union { i32x4 i; bf16x8 h; } u; u.i = v; return u.h; }

DEV float fast_tanh(float z){
  z = fminf(15.f, fmaxf(-15.f, z));
  float e = __expf(2.f * z);
  return (e - 1.f) / (e + 1.f);
}
DEV float fast_sigm(float z){
  z = fminf(30.f, fmaxf(-30.f, z));
  return 1.f / (1.f + __expf(-z));
}

DEV float wred(float v){
  #pragma unroll
  for (int o = 32; o > 0; o >>= 1) v += __shfl_xor(v, o, 64);
  return v;
}

// ---------------- init: zero counters + h parity-0 buffers ----------------
__global__ void k_init(char* ws){
  const u32 n0 = 4096, n1 = 32768, n2 = 32768, n3 = 8192, n4 = 8192; // words
  const u32 tot = n0 + n1 + n2 + n3 + n4;
  u32 idx = blockIdx.x * blockDim.x + threadIdx.x;
  u32 stride = gridDim.x * blockDim.x;
  for (u32 k = idx; k < tot; k += stride){
    u32 r = k; u32 off;
    if (r < n0) off = r * 4u;
    else { r -= n0;
      if (r < n1) off = OFF_HX + r * 4u;
      else { r -= n1;
        if (r < n2) off = OFF_HX + 262144u + r * 4u;
        else { r -= n2;
          if (r < n3) off = OFF_GX + r * 4u;
          else { r -= n3; off = OFF_GX + 65536u + r * 4u; } } } }
    *(u32*)(ws + off) = 0u;
  }
}

// ---------------- prep: build packed bf16 B-fragment images ----------------
__global__ void k_prep(const float* __restrict__ Win, const float* __restrict__ Wres,
                       const float* __restrict__ Wih, const float* __restrict__ Whh, char* ws){
  const u32 NE = 64u * 18u * 4096u;   // 4718592
  const u32 NG = 16u * 6u * 12288u;   // 1179648
  u32 idx0 = blockIdx.x * blockDim.x + threadIdx.x;
  u32 stride = gridDim.x * blockDim.x;
  for (u32 idx = idx0; idx < NE + NG; idx += stride){
    if (idx < NE){
      u32 j = idx / 73728u, r = idx % 73728u;
      u32 c = r / 4096u,    e = r % 4096u;
      u32 kg = e >> 10, col = (e >> 5) & 31u, ko = e & 31u;
      u32 gcol = j * 32u + col;
      u32 out = OFF_BE + j * 147456u + c * 8192u + e * 2u;
      u32 val;
      if (c < 16u){
        u32 k = c * 128u + kg * 32u + ko;
        val = f2bf(Wres[k * 2048u + gcol]);
      } else {
        u32 sub = c - 16u, sel = kg >> 1, kg2 = kg & 1u;
        u32 k = sub * 64u + kg2 * 32u + ko;
        float wv = Win[k * 2048u + gcol];
        u32 hi = f2bf(wv);
        val = sel ? f2bf(wv - bf2f(hi)) : hi;
      }
      *(unsigned short*)(ws + out) = (unsigned short)val;
    } else {
      u32 id = idx - NE;
      u32 j = id / 73728u, r = id % 73728u;
      u32 c = r / 12288u,  e = r % 12288u;
      u32 kg = e / 3072u, col = (e >> 5) % 96u, ko = e & 31u;
      u32 gate = col >> 5, jj = col & 31u;
      u32 g = gate * 512u + j * 32u + jj;
      u32 out = OFF_BG + j * 147456u + c * 24576u + e * 2u;
      u32 val;
      if (c < 4u){
        u32 k = c * 128u + kg * 32u + ko;
        val = f2bf(Whh[g * 512u + k]);
      } else {
        u32 sub = c - 4u, sel = kg >> 1, kg2 = kg & 1u;
        u32 k = sub * 64u + kg2 * 32u + ko;
        float wv = Wih[g * 128u + k];
        u32 hi = f2bf(wv);
        val = sel ? f2bf(wv - bf2f(hi)) : hi;
      }
      *(unsigned short*)(ws + out) = (unsigned short)val;
    }
  }
}

// ---------------- scan kernel ----------------
struct FS { i32x4 a0,a1,a2,a3,b0,b1,b2,b3; };
struct GS { i32x4 a[8]; i32x4 b[12]; };

DEV void esn_ih(FS& S, const char* pa, const char* pb){
  S.a0 = ld4o_sc<0>(pa);    S.a1 = ld4o_sc<1024>(pa);
  S.a2 = ld4o_sc<2048>(pa); S.a3 = ld4o_sc<3072>(pa);
  S.b0 = ld4o<0>(pb);       S.b1 = ld4o<1024>(pb);
  S.b2 = ld4o<2048>(pb);    S.b3 = ld4o<3072>(pb);
}
DEV void esn_ix(FS& S, const float* xb, const float* xb2, const char* ph, const char* pl){
  S.a0 = ld4o<0>(xb);  S.a1 = ld4o<16>(xb);
  S.a2 = ld4o<0>(xb2); S.a3 = ld4o<16>(xb2);
  S.b0 = ld4o<0>(ph);  S.b1 = ld4o<1024>(ph);
  S.b2 = ld4o<0>(pl);  S.b3 = ld4o<1024>(pl);
}
DEV void esn_ch(FS& S, f32x4& a00, f32x4& a01, f32x4& a10, f32x4& a11){
  a00 = mfma16(as_bf(S.a0), as_bf(S.b0), a00);
  a01 = mfma16(as_bf(S.a0), as_bf(S.b1), a01);
  a10 = mfma16(as_bf(S.a1), as_bf(S.b0), a10);
  a11 = mfma16(as_bf(S.a1), as_bf(S.b1), a11);
  a00 = mfma16(as_bf(S.a2), as_bf(S.b2), a00);
  a01 = mfma16(as_bf(S.a2), as_bf(S.b3), a01);
  a10 = mfma16(as_bf(S.a3), as_bf(S.b2), a10);
  a11 = mfma16(as_bf(S.a3), as_bf(S.b3), a11);
}
DEV void esn_cx(FS& S, f32x4& a00, f32x4& a01, f32x4& a10, f32x4& a11){
  bf16x8 ah, al, ah2, al2;
  #pragma unroll
  for (int e = 0; e < 4; ++e){
    float f = __uint_as_float((u32)S.a0[e]); u32 h = f2bf(f);
    ah[e] = (short)h; al[e] = (short)f2bf(f - bf2f(h));
  }
  #pragma unroll
  for (int e = 0; e < 4; ++e){
    float f = __uint_as_float((u32)S.a1[e]); u32 h = f2bf(f);
    ah[4+e] = (short)h; al[4+e] = (short)f2bf(f - bf2f(h));
  }
  #pragma unroll
  for (int e = 0; e < 4; ++e){
    float f = __uint_as_float((u32)S.a2[e]); u32 h = f2bf(f);
    ah2[e] = (short)h; al2[e] = (short)f2bf(f - bf2f(h));
  }
  #pragma unroll
  for (int e = 0; e < 4; ++e){
    float f = __uint_as_float((u32)S.a3[e]); u32 h = f2bf(f);
    ah2[4+e] = (short)h; al2[4+e] = (short)f2bf(f - bf2f(h));
  }
  bf16x8 bh0 = as_bf(S.b0), bh1 = as_bf(S.b1), bl0 = as_bf(S.b2), bl1 = as_bf(S.b3);
  a00 = mfma16(ah, bh0, a00);  a00 = mfma16(ah, bl0, a00);  a00 = mfma16(al, bh0, a00);
  a01 = mfma16(ah, bh1, a01);  a01 = mfma16(ah, bl1, a01);  a01 = mfma16(al, bh1, a01);
  a10 = mfma16(ah2, bh0, a10); a10 = mfma16(ah2, bl0, a10); a10 = mfma16(al2, bh0, a10);
  a11 = mfma16(ah2, bh1, a11); a11 = mfma16(ah2, bl1, a11); a11 = mfma16(al2, bh1, a11);
}

DEV void gru_ih(GS& S, const char* pa, const char* pb, int offA, int offB){
  #pragma unroll
  for (int kg = 0; kg < 4; ++kg){
    S.a[kg*2+0] = ld4_sc(pa + kg*2048 + offA);
    S.a[kg*2+1] = ld4_sc(pa + kg*2048 + 1024 + offA);
    #pragma unroll
    for (int g = 0; g < 3; ++g)
      S.b[kg*3+g] = ld4(pb + kg*6144 + g*2048 + offB);
  }
}
DEV void gru_ix(GS& S, const float* xb, const float* xb2, const char* pbx, int offB){
  #pragma unroll
  for (int kg2 = 0; kg2 < 2; ++kg2){
    S.a[(kg2*2+0)*2]   = ld4(xb  + kg2*32);
    S.a[(kg2*2+0)*2+1] = ld4(xb  + kg2*32 + 4);
    S.a[(kg2*2+1)*2]   = ld4(xb2 + kg2*32);
    S.a[(kg2*2+1)*2+1] = ld4(xb2 + kg2*32 + 4);
    #pragma unroll
    for (int sel = 0; sel < 2; ++sel)
      #pragma unroll
      for (int g = 0; g < 3; ++g)
        S.b[(sel*2+kg2)*3+g] = ld4(pbx + (sel*2+kg2)*6144 + g*2048 + offB);
  }
}
DEV void gru_ch(GS& S, f32x4* aR, f32x4* aZ, f32x4* aNH){
  #pragma unroll
  for (int kg = 0; kg < 4; ++kg)
    #pragma unroll
    for (int mt = 0; mt < 2; ++mt){
      bf16x8 a = as_bf(S.a[kg*2+mt]);
      aR[mt]  = mfma16(a, as_bf(S.b[kg*3+0]), aR[mt]);
      aZ[mt]  = mfma16(a, as_bf(S.b[kg*3+1]), aZ[mt]);
      aNH[mt] = mfma16(a, as_bf(S.b[kg*3+2]), aNH[mt]);
    }
}
DEV void gru_cx(GS& S, f32x4* aR, f32x4* aZ, f32x4* aNX){
  #pragma unroll
  for (int kg2 = 0; kg2 < 2; ++kg2)
    #pragma unroll
    for (int mt = 0; mt < 2; ++mt){
      bf16x8 ah, al;
      i32x4 r0 = S.a[(kg2*2+mt)*2], r1 = S.a[(kg2*2+mt)*2+1];
      #pragma unroll
      for (int e = 0; e < 4; ++e){
        float f = __uint_as_float((u32)r0[e]); u32 h = f2bf(f);
        ah[e] = (short)h; al[e] = (short)f2bf(f - bf2f(h));
      }
      #pragma unroll
      for (int e = 0; e < 4; ++e){
        float f = __uint_as_float((u32)r1[e]); u32 h = f2bf(f);
        ah[4+e] = (short)h; al[4+e] = (short)f2bf(f - bf2f(h));
      }
      {
        bf16x8 bh = as_bf(S.b[(0*2+kg2)*3+0]), bl = as_bf(S.b[(1*2+kg2)*3+0]);
        aR[mt] = mfma16(ah, bh, aR[mt]); aR[mt] = mfma16(ah, bl, aR[mt]); aR[mt] = mfma16(al, bh, aR[mt]);
      }
      {
        bf16x8 bh = as_bf(S.b[(0*2+kg2)*3+1]), bl = as_bf(S.b[(1*2+kg2)*3+1]);
        aZ[mt] = mfma16(ah, bh, aZ[mt]); aZ[mt] = mfma16(ah, bl, aZ[mt]); aZ[mt] = mfma16(al, bh, aZ[mt]);
      }
      {
        bf16x8 bh = as_bf(S.b[(0*2+kg2)*3+2]), bl = as_bf(S.b[(1*2+kg2)*3+2]);
        aNX[mt] = mfma16(ah, bh, aNX[mt]); aNX[mt] = mfma16(ah, bl, aNX[mt]); aNX[mt] = mfma16(al, bh, aNX[mt]);
      }
    }
}

__launch_bounds__(128, 1)
__global__ void k_scan(const float* __restrict__ x, char* ws,
                       const float* __restrict__ b_ih, const float* __restrict__ b_hh){
  __shared__ f32x4 mrg[2][4][64];
  const int bid = blockIdx.x;
  const int tid = threadIdx.x;
  const int lane = tid & 63;
  const int w = tid >> 6;
  const int l15 = lane & 15, l4 = lane >> 4;
  const int offA = l15*64 + l4*16;

  if (bid < 128){
    // =============== ESN: group gi (32 batches), panel j (32 cols of R) ===============
    const int gi = bid >> 6, j = bid & 63;
    u32* cntE = (u32*)(ws + OFF_CNT_E);
    const char* Bp = ws + OFF_BE + (size_t)j * 147456u;
    char* hXb = ws + OFF_HX + (size_t)gi * 262144u;
    float* ehf = (float*)(ws + OFF_EHF);

    const char* Bpo  = Bp + w*4096 + offA;                 // h-chunk B base
    const char* pbx0 = Bp + 16*8192 + w*2048 + offA;       // x sub0 B (hi at +0, lo at +4096)
    const char* pbx1 = Bp + 17*8192 + w*2048 + offA;       // x sub1 B
    const char* hbase = hXb + w*4096 + offA;
    const float* xrow = x + (size_t)(gi*32 + l15) * (TT*II) + w*32 + l4*8;

    f32x4 h00 = {0,0,0,0}, h01 = {0,0,0,0}, h10 = {0,0,0,0}, h11 = {0,0,0,0};

    for (int t = 0; t < TT; ++t){
      const char* hAo = hbase + (t & 1) * 131072;
      char* hW = hXb + ((t + 1) & 1) * 131072;
      f32x4 a00 = {0,0,0,0}, a01 = {0,0,0,0}, a10 = {0,0,0,0}, a11 = {0,0,0,0};
      FS S0, S1, S2, S3;
      const float* xb  = xrow + (size_t)t * II;
      const float* xb2 = xb + (size_t)16 * TT * II;

      esn_ix(S0, xb, xb2, pbx0, pbx0 + 4096);
      esn_ix(S1, xb + 64, xb2 + 64, pbx1, pbx1 + 4096);
      if (t) poll_ge(cntE + t*2 + gi, 64u);
      else { asm volatile("s_waitcnt vmcnt(0)" ::: "memory"); }
      __builtin_amdgcn_sched_barrier(0);
      esn_cx(S0, a00, a01, a10, a11);
      esn_cx(S1, a00, a01, a10, a11);

      esn_ih(S0, hAo + 0*8192, Bpo + 0*8192);
      esn_ih(S1, hAo + 1*8192, Bpo + 1*8192);
      esn_ih(S2, hAo + 2*8192, Bpo + 2*8192);
      #pragma unroll
      for (int u = 0; u < 16; ++u){
        if (u + 3 < 16){
          const int kn = u + 3;
          if ((u & 3) == 0)      esn_ih(S3, hAo + kn*8192, Bpo + kn*8192);
          else if ((u & 3) == 1) esn_ih(S0, hAo + kn*8192, Bpo + kn*8192);
          else if ((u & 3) == 2) esn_ih(S1, hAo + kn*8192, Bpo + kn*8192);
          else                   esn_ih(S2, hAo + kn*8192, Bpo + kn*8192);
        }
        if (u < 13) WAITV(24);
        else if (u == 13) WAITV(16);
        else if (u == 14) WAITV(8);
        else WAITV(0);
        if ((u & 3) == 0)      esn_ch(S0, a00, a01, a10, a11);
        else if ((u & 3) == 1) esn_ch(S1, a00, a01, a10, a11);
        else if ((u & 3) == 2) esn_ch(S2, a00, a01, a10, a11);
        else                   esn_ch(S3, a00, a01, a10, a11);
      }

      if (w){
        mrg[t&1][0][lane] = a00; mrg[t&1][1][lane] = a01;
        mrg[t&1][2][lane] = a10; mrg[t&1][3][lane] = a11;
      }
      __syncthreads();
      if (!w){
        a00 += mrg[t&1][0][lane]; a01 += mrg[t&1][1][lane];
        a10 += mrg[t&1][2][lane]; a11 += mrg[t&1][3][lane];
        #pragma unroll
        for (int mt = 0; mt < 2; ++mt)
          #pragma unroll
          for (int nt = 0; nt < 2; ++nt){
            f32x4& av = mt ? (nt ? a11 : a10) : (nt ? a01 : a00);
            f32x4& hv = mt ? (nt ? h11 : h10) : (nt ? h01 : h00);
            #pragma unroll
            for (int q = 0; q < 4; ++q){
              float cand = fast_tanh(av[q]);
              float hn = 0.7f * hv[q] + 0.3f * cand;
              hv[q] = hn;
              int m = mt*16 + l4*4 + q;
              int ko = nt*16 + l15;
              st2_sc(hW + (size_t)((j*32 + m)*32 + ko) * 2, f2bf(hn));
              if (t == TT - 1) ehf[(size_t)(gi*32 + m) * 2048 + j*32 + ko] = hn;
            }
          }
        asm volatile("s_waitcnt vmcnt(0)" ::: "memory");
        if (lane == 0) atomicAdd(cntE + (t+1)*2 + gi, 1u);
      }
    }
  } else {
    // =============== GRU: group gi (32 batches), panel jp (32 of H); wave w owns 16 j's ===============
    const int gb = bid - 128;
    const int gi = gb >> 4, jp = gb & 15;
    u32* cntG = (u32*)(ws + OFF_CNT_G);
    const char* Bp = ws + OFF_BG + (size_t)jp * 147456u;
    char* gXb = ws + OFF_GX + (size_t)gi * 65536u;
    float* ghf = (float*)(ws + OFF_GHF);
    const int j = jp*32 + w*16 + l15;
    const float bR  = b_ih[j] + b_hh[j];
    const float bZ  = b_ih[512 + j] + b_hh[512 + j];
    const float bNX = b_ih[1024 + j];
    const float bNH = b_hh[1024 + j];
    const int offB = (w*16 + l15)*64 + l4*16;
    const char* pbx0 = Bp + 4*24576;
    const char* pbx1 = Bp + 5*24576;
    const float* xrow = x + (size_t)(gi*32 + l15) * (TT*II) + l4*8;

    f32x4 hold[2] = {{0,0,0,0},{0,0,0,0}};

    for (int t = 0; t < TT; ++t){
      const char* hA = gXb + (t & 1) * 32768;
      char* hW = gXb + ((t + 1) & 1) * 32768;
      f32x4 aR[2]  = {{0,0,0,0},{0,0,0,0}};
      f32x4 aZ[2]  = {{0,0,0,0},{0,0,0,0}};
      f32x4 aNH[2] = {{0,0,0,0},{0,0,0,0}};
      f32x4 aNX[2] = {{0,0,0,0},{0,0,0,0}};
      GS S0, S1;
      const float* xb  = xrow + (size_t)t * II;
      const float* xb2 = xb + (size_t)16 * TT * II;

      gru_ix(S0, xb, xb2, pbx0, offB);
      gru_ix(S1, xb + 64, xb2 + 64, pbx1, offB);
      if (t) poll_ge(cntG + t*2 + gi, 16u);
      else { asm volatile("s_waitcnt vmcnt(0)" ::: "memory"); }
      __builtin_amdgcn_sched_barrier(0);
      gru_cx(S0, aR, aZ, aNX);
      gru_ih(S0, hA + 0*8192, Bp + 0*24576, offA, offB);
      gru_cx(S1, aR, aZ, aNX);
      gru_ih(S1, hA + 1*8192, Bp + 1*24576, offA, offB);
      #pragma unroll
      for (int u = 0; u < 4; ++u){
        if (u < 3) WAITV(20); else WAITV(0);
        if (u & 1){
          gru_ch(S1, aR, aZ, aNH);
          if (u + 2 < 4) gru_ih(S1, hA + (u+2)*8192, Bp + (size_t)(u+2)*24576, offA, offB);
        } else {
          gru_ch(S0, aR, aZ, aNH);
          if (u + 2 < 4) gru_ih(S0, hA + (u+2)*8192, Bp + (size_t)(u+2)*24576, offA, offB);
        }
      }
      #pragma unroll
      for (int mt = 0; mt < 2; ++mt)
        #pragma unroll
        for (int q = 0; q < 4; ++q){
          float rv = fast_sigm(aR[mt][q] + bR);
          float zv = fast_sigm(aZ[mt][q] + bZ);
          float nv = fast_tanh(aNX[mt][q] + bNX + rv * (aNH[mt][q] + bNH));
          float hn = (1.f - zv) * nv + zv * hold[mt][q];
          hold[mt][q] = hn;
          int m = mt*16 + l4*4 + q;
          st2_sc(hW + (size_t)((jp*32 + m)*32 + w*16 + l15) * 2, f2bf(hn));
          if (t == TT - 1) ghf[(size_t)(gi*32 + m) * 512 + j] = hn;
        }
      asm volatile("s_waitcnt vmcnt(0)" ::: "memory");
      __syncthreads();
      if (tid == 0) atomicAdd(cntG + (t+1)*2 + gi, 1u);
    }
  }
}

// ---------------- f32 epilogue kernels ----------------
__global__ void k_proj(char* ws, const float* __restrict__ pW, const float* __restrict__ pb){
  const float* ehf = (const float*)(ws + OFF_EHF);
  float* proj = (float*)(ws + OFF_PROJ);
  __shared__ float arow[2048];
  int b = blockIdx.x >> 3, jg = blockIdx.x & 7;
  for (int k = threadIdx.x; k < 2048; k += 256) arow[k] = ehf[(size_t)b*2048 + k];
  __syncthreads();
  int wv = threadIdx.x >> 6, lane = threadIdx.x & 63;
  for (int jj = 0; jj < 16; ++jj){
    int jq = jg*64 + wv*16 + jj;
    const float* wr = pW + (size_t)jq * 2048;
    float s = 0.f;
    #pragma unroll 4
    for (int u = 0; u < 32; ++u) s = fmaf(arow[lane + 64*u], wr[lane + 64*u], s);
    s = wred(s);
    if (lane == 0) proj[b*512 + jq] = s + pb[jq];
  }
}

__global__ void k_gate(char* ws, const float* __restrict__ gW, const float* __restrict__ gb){
  const float* proj = (const float*)(ws + OFF_PROJ);
  const float* ghf  = (const float*)(ws + OFF_GHF);
  float* comb = (float*)(ws + OFF_COMB);
  __shared__ float pr[512], gr[512];
  int b = blockIdx.x >> 3, jg = blockIdx.x & 7;
  for (int k = threadIdx.x; k < 512; k += 256){ pr[k] = proj[b*512 + k]; gr[k] = ghf[b*512 + k]; }
  __syncthreads();
  int wv = threadIdx.x >> 6, lane = threadIdx.x & 63;
  for (int jj = 0; jj < 16; ++jj){
    int jq = jg*64 + wv*16 + jj;
    const float* wr = gW + (size_t)jq * 1024;
    float s = 0.f;
    #pragma unroll
    for (int u = 0; u < 8; ++u) s = fmaf(pr[lane + 64*u], wr[lane + 64*u], s);
    #pragma unroll
    for (int u = 0; u < 8; ++u) s = fmaf(gr[lane + 64*u], wr[512 + lane + 64*u], s);
    s = wred(s);
    if (lane == 0){
      float g = fast_sigm(s + gb[jq]);
      comb[b*512 + jq] = g * pr[jq] + (1.f - g) * gr[jq];
    }
  }
}

__global__ void k_head1(char* ws, const float* __restrict__ W1, const float* __restrict__ b1){
  const float* comb = (const float*)(ws + OFF_COMB);
  float* hid = (float*)(ws + OFF_HID);
  __shared__ float cr[512];
  int b = blockIdx.x >> 3, jg = blockIdx.x & 7;
  for (int k = threadIdx.x; k < 512; k += 256) cr[k] = comb[b*512 + k];
  __syncthreads();
  int wv = threadIdx.x >> 6, lane = threadIdx.x & 63;
  for (int jj = 0; jj < 16; ++jj){
    int jq = jg*64 + wv*16 + jj;
    const float* wr = W1 + (size_t)jq * 512;
    float s = 0.f;
    #pragma unroll
    for (int u = 0; u < 8; ++u) s = fmaf(cr[lane + 64*u], wr[lane + 64*u], s);
    s = wred(s);
    if (lane == 0) hid[b*512 + jq] = fmaxf(0.f, s + b1[jq]);
  }
}

__global__ void k_head2(char* ws, const float* __restrict__ W2, const float* __restrict__ b2, float* __restrict__ out){
  const float* hid = (const float*)(ws + OFF_HID);
  __shared__ float hr[512];
  int b = blockIdx.x >> 1, jg = blockIdx.x & 1;
  for (int k = threadIdx.x; k < 512; k += 256) hr[k] = hid[b*512 + k];
  __syncthreads();
  int wv = threadIdx.x >> 6, lane = threadIdx.x & 63;
  for (int jj = 0; jj < 16; ++jj){
    int jq = jg*64 + wv*16 + jj;
    const float* wr = W2 + (size_t)jq * 512;
    float s = 0.f;
    #pragma unroll
    for (int u = 0; u < 8; ++u) s = fmaf(hr[lane + 64*u], wr[lane + 64*u], s);
    s = wred(s);
    if (lane == 0) out[b*128 + jq] = s + b2[jq];
  }
}

// ---------------- launch ----------------
extern "C" void kernel_launch(void* const* d_in, const int* in_sizes, int n_in,
                              void* d_out, int out_size, void* d_ws, size_t ws_size,
                              hipStream_t stream){
  const float* x    = (const float*)d_in[0];
  const float* Win  = (const float*)d_in[1];
  const float* Wres = (const float*)d_in[2];
  const float* Wih  = (const float*)d_in[3];
  const float* Whh  = (const float*)d_in[4];
  const float* bih  = (const float*)d_in[5];
  const float* bhh  = (const float*)d_in[6];
  const float* pW   = (const float*)d_in[7];
  const float* pb   = (const float*)d_in[8];
  const float* gW   = (const float*)d_in[9];
  const float* gb   = (const float*)d_in[10];
  const float* W1   = (const float*)d_in[11];
  const float* b1   = (const float*)d_in[12];
  const float* W2   = (const float*)d_in[13];
  const float* b2   = (const float*)d_in[14];
  char* ws = (char*)d_ws;
  float* out = (float*)d_out;

  k_init<<<dim3(336), dim3(256), 0, stream>>>(ws);
  k_prep<<<dim3(8192), dim3(256), 0, stream>>>(Win, Wres, Wih, Whh, ws);
  k_scan<<<dim3(160), dim3(128), 0, stream>>>(x, ws, bih, bhh);
  k_proj<<<dim3(512), dim3(256), 0, stream>>>(ws, pW, pb);
  k_gate<<<dim3(512), dim3(256), 0, stream>>>(ws, gW, gb);
  k_head1<<<dim3(512), dim3(256), 0, stream>>>(ws, W1, b1);
  k_head2<<<dim3(128), dim3(256), 0, stream>>>(ws, W2, b2, out);
}

// Round 3
// 5315.871 us; speedup vs baseline: 1.1994x; 1.1994x over previous
//
#include <hip/hip_runtime.h>
#include <cstdint>
#include <cstddef>

typedef unsigned int u32;
typedef float  f32x4  __attribute__((ext_vector_type(4)));
typedef int    i32x4  __attribute__((ext_vector_type(4)));
typedef short  bf16x8 __attribute__((ext_vector_type(8)));

#define DEV static __device__ __forceinline__

#define TT 512
#define II 128

// ---------------- workspace layout (bytes) ----------------
#define OFF_FLG_E 0u
#define OFF_FLG_G 8192u
#define OFF_HX    16384u                    // 2 groups * 2 parity * 131072
#define OFF_GX    (OFF_HX + 524288u)        // 2 * 2 * 32768
#define OFF_BE    (OFF_GX + 131072u)        // 64 panels * 18 chunks * 8192
#define OFF_BG    (OFF_BE + 9437184u)       // 16 panels * 6 chunks * 24576
#define OFF_EHF   (OFF_BG + 2359296u)       // 64*2048*4
#define OFF_GHF   (OFF_EHF + 524288u)       // 64*512*4
#define OFF_PROJ  (OFF_GHF + 131072u)
#define OFF_COMB  (OFF_PROJ + 131072u)
#define OFF_HID   (OFF_COMB + 131072u)

// ---------------- small helpers ----------------
DEV u32 f2bf(float f){ u32 u = __float_as_uint(f); return (u + 0x7FFFu + ((u >> 16) & 1u)) >> 16; }
DEV float bf2f(u32 s){ return __uint_as_float(s << 16); }

DEV i32x4 ld4_sc(const void* p){ i32x4 r; asm volatile("global_load_dwordx4 %0, %1, off sc0 sc1" : "=v"(r) : "v"(p)); return r; }
DEV i32x4 ld4(const void* p){ i32x4 r; asm volatile("global_load_dwordx4 %0, %1, off" : "=v"(r) : "v"(p)); return r; }
template<int OFF> DEV i32x4 ld4o(const void* p){ i32x4 r; asm volatile("global_load_dwordx4 %0, %1, off offset:%c2" : "=v"(r) : "v"(p), "n"(OFF)); return r; }
template<int OFF> DEV i32x4 ld4o_sc(const void* p){ i32x4 r; asm volatile("global_load_dwordx4 %0, %1, off offset:%c2 sc0 sc1" : "=v"(r) : "v"(p), "n"(OFF)); return r; }
DEV void st2_sc(void* p, u32 v){ asm volatile("global_store_short %0, %1, off sc0 sc1" :: "v"(p), "v"(v)); }
DEV void st4_sc(void* p, u32 v){ asm volatile("global_store_dword %0, %1, off sc0 sc1" :: "v"(p), "v"(v)); }

#define WAITV(n) do { asm volatile("s_waitcnt vmcnt(" #n ")" ::: "memory"); __builtin_amdgcn_sched_barrier(0); } while(0)

// all lanes poll their own flag word; exit when every lane's flag >= tgt
DEV void poll_all(const u32* p, u32 tgt){
  for (int it = 0; it < (1 << 22); ++it){
    u32 v;
    asm volatile("global_load_dword %0, %1, off sc0 sc1\n\ts_waitcnt vmcnt(0)" : "=v"(v) : "v"(p) : "memory");
    if (__all((int)(v >= tgt))) return;
    __builtin_amdgcn_s_sleep(1);
  }
}

DEV f32x4 mfma16(bf16x8 a, bf16x8 b, f32x4 c){ return __builtin_amdgcn_mfma_f32_16x16x32_bf16(a, b, c, 0, 0, 0); }
DEV bf16x8 as_bf(i32x4 v){ union { i32x4 i; bf16x8 h; } u; u.i = v; return u.h; }

DEV float fast_tanh(float z){
  z = fminf(15.f, fmaxf(-15.f, z));
  float e = __expf(2.f * z);
  return (e - 1.f) / (e + 1.f);
}
DEV float fast_sigm(float z){
  z = fminf(30.f, fmaxf(-30.f, z));
  return 1.f / (1.f + __expf(-z));
}

DEV float wred(float v){
  #pragma unroll
  for (int o = 32; o > 0; o >>= 1) v += __shfl_xor(v, o, 64);
  return v;
}

// ---------------- init: zero flags + h parity-0 buffers ----------------
__global__ void k_init(char* ws){
  const u32 n0 = 4096, n1 = 32768, n2 = 32768, n3 = 8192, n4 = 8192; // words
  const u32 tot = n0 + n1 + n2 + n3 + n4;
  u32 idx = blockIdx.x * blockDim.x + threadIdx.x;
  u32 stride = gridDim.x * blockDim.x;
  for (u32 k = idx; k < tot; k += stride){
    u32 r = k; u32 off;
    if (r < n0) off = r * 4u;
    else { r -= n0;
      if (r < n1) off = OFF_HX + r * 4u;
      else { r -= n1;
        if (r < n2) off = OFF_HX + 262144u + r * 4u;
        else { r -= n2;
          if (r < n3) off = OFF_GX + r * 4u;
          else { r -= n3; off = OFF_GX + 65536u + r * 4u; } } } }
    *(u32*)(ws + off) = 0u;
  }
}

// ---------------- prep: build packed bf16 B-fragment images ----------------
__global__ void k_prep(const float* __restrict__ Win, const float* __restrict__ Wres,
                       const float* __restrict__ Wih, const float* __restrict__ Whh, char* ws){
  const u32 NE = 64u * 18u * 4096u;   // 4718592
  const u32 NG = 16u * 6u * 12288u;   // 1179648
  u32 idx0 = blockIdx.x * blockDim.x + threadIdx.x;
  u32 stride = gridDim.x * blockDim.x;
  for (u32 idx = idx0; idx < NE + NG; idx += stride){
    if (idx < NE){
      u32 j = idx / 73728u, r = idx % 73728u;
      u32 c = r / 4096u,    e = r % 4096u;
      u32 kg = e >> 10, col = (e >> 5) & 31u, ko = e & 31u;
      u32 gcol = j * 32u + col;
      u32 out = OFF_BE + j * 147456u + c * 8192u + e * 2u;
      u32 val;
      if (c < 16u){
        u32 k = c * 128u + kg * 32u + ko;
        val = f2bf(Wres[k * 2048u + gcol]);
      } else {
        u32 sub = c - 16u, sel = kg >> 1, kg2 = kg & 1u;
        u32 k = sub * 64u + kg2 * 32u + ko;
        float wv = Win[k * 2048u + gcol];
        u32 hi = f2bf(wv);
        val = sel ? f2bf(wv - bf2f(hi)) : hi;
      }
      *(unsigned short*)(ws + out) = (unsigned short)val;
    } else {
      u32 id = idx - NE;
      u32 j = id / 73728u, r = id % 73728u;
      u32 c = r / 12288u,  e = r % 12288u;
      u32 kg = e / 3072u, col = (e >> 5) % 96u, ko = e & 31u;
      u32 gate = col >> 5, jj = col & 31u;
      u32 g = gate * 512u + j * 32u + jj;
      u32 out = OFF_BG + j * 147456u + c * 24576u + e * 2u;
      u32 val;
      if (c < 4u){
        u32 k = c * 128u + kg * 32u + ko;
        val = f2bf(Whh[g * 512u + k]);
      } else {
        u32 sub = c - 4u, sel = kg >> 1, kg2 = kg & 1u;
        u32 k = sub * 64u + kg2 * 32u + ko;
        float wv = Wih[g * 128u + k];
        u32 hi = f2bf(wv);
        val = sel ? f2bf(wv - bf2f(hi)) : hi;
      }
      *(unsigned short*)(ws + out) = (unsigned short)val;
    }
  }
}

// ---------------- scan kernel ----------------
struct FS { i32x4 a0,a1,a2,a3,b0,b1,b2,b3; };
struct GS { i32x4 a[8]; i32x4 b[12]; };

DEV void esn_ih(FS& S, const char* pa, const char* pb){
  S.a0 = ld4o_sc<0>(pa);    S.a1 = ld4o_sc<1024>(pa);
  S.a2 = ld4o_sc<2048>(pa); S.a3 = ld4o_sc<3072>(pa);
  S.b0 = ld4o<0>(pb);       S.b1 = ld4o<1024>(pb);
  S.b2 = ld4o<2048>(pb);    S.b3 = ld4o<3072>(pb);
}
DEV void esn_ix(FS& S, const float* xb, const float* xb2, const char* ph, const char* pl){
  S.a0 = ld4o<0>(xb);  S.a1 = ld4o<16>(xb);
  S.a2 = ld4o<0>(xb2); S.a3 = ld4o<16>(xb2);
  S.b0 = ld4o<0>(ph);  S.b1 = ld4o<1024>(ph);
  S.b2 = ld4o<0>(pl);  S.b3 = ld4o<1024>(pl);
}
DEV void esn_ch(FS& S, f32x4& a00, f32x4& a01, f32x4& a10, f32x4& a11){
  a00 = mfma16(as_bf(S.a0), as_bf(S.b0), a00);
  a01 = mfma16(as_bf(S.a0), as_bf(S.b1), a01);
  a10 = mfma16(as_bf(S.a1), as_bf(S.b0), a10);
  a11 = mfma16(as_bf(S.a1), as_bf(S.b1), a11);
  a00 = mfma16(as_bf(S.a2), as_bf(S.b2), a00);
  a01 = mfma16(as_bf(S.a2), as_bf(S.b3), a01);
  a10 = mfma16(as_bf(S.a3), as_bf(S.b2), a10);
  a11 = mfma16(as_bf(S.a3), as_bf(S.b3), a11);
}
DEV void esn_cx(FS& S, f32x4& a00, f32x4& a01, f32x4& a10, f32x4& a11){
  bf16x8 ah, al, ah2, al2;
  #pragma unroll
  for (int e = 0; e < 4; ++e){
    float f = __uint_as_float((u32)S.a0[e]); u32 h = f2bf(f);
    ah[e] = (short)h; al[e] = (short)f2bf(f - bf2f(h));
  }
  #pragma unroll
  for (int e = 0; e < 4; ++e){
    float f = __uint_as_float((u32)S.a1[e]); u32 h = f2bf(f);
    ah[4+e] = (short)h; al[4+e] = (short)f2bf(f - bf2f(h));
  }
  #pragma unroll
  for (int e = 0; e < 4; ++e){
    float f = __uint_as_float((u32)S.a2[e]); u32 h = f2bf(f);
    ah2[e] = (short)h; al2[e] = (short)f2bf(f - bf2f(h));
  }
  #pragma unroll
  for (int e = 0; e < 4; ++e){
    float f = __uint_as_float((u32)S.a3[e]); u32 h = f2bf(f);
    ah2[4+e] = (short)h; al2[4+e] = (short)f2bf(f - bf2f(h));
  }
  bf16x8 bh0 = as_bf(S.b0), bh1 = as_bf(S.b1), bl0 = as_bf(S.b2), bl1 = as_bf(S.b3);
  a00 = mfma16(ah, bh0, a00);  a00 = mfma16(ah, bl0, a00);  a00 = mfma16(al, bh0, a00);
  a01 = mfma16(ah, bh1, a01);  a01 = mfma16(ah, bl1, a01);  a01 = mfma16(al, bh1, a01);
  a10 = mfma16(ah2, bh0, a10); a10 = mfma16(ah2, bl0, a10); a10 = mfma16(al2, bh0, a10);
  a11 = mfma16(ah2, bh1, a11); a11 = mfma16(ah2, bl1, a11); a11 = mfma16(al2, bh1, a11);
}

DEV void gru_ih(GS& S, const char* pa, const char* pb, int offA, int offB){
  #pragma unroll
  for (int kg = 0; kg < 4; ++kg){
    S.a[kg*2+0] = ld4_sc(pa + kg*2048 + offA);
    S.a[kg*2+1] = ld4_sc(pa + kg*2048 + 1024 + offA);
    #pragma unroll
    for (int g = 0; g < 3; ++g)
      S.b[kg*3+g] = ld4(pb + kg*6144 + g*2048 + offB);
  }
}
DEV void gru_ix(GS& S, const float* xb, const float* xb2, const char* pbx, int offB){
  #pragma unroll
  for (int kg2 = 0; kg2 < 2; ++kg2){
    S.a[(kg2*2+0)*2]   = ld4(xb  + kg2*32);
    S.a[(kg2*2+0)*2+1] = ld4(xb  + kg2*32 + 4);
    S.a[(kg2*2+1)*2]   = ld4(xb2 + kg2*32);
    S.a[(kg2*2+1)*2+1] = ld4(xb2 + kg2*32 + 4);
    #pragma unroll
    for (int sel = 0; sel < 2; ++sel)
      #pragma unroll
      for (int g = 0; g < 3; ++g)
        S.b[(sel*2+kg2)*3+g] = ld4(pbx + (sel*2+kg2)*6144 + g*2048 + offB);
  }
}
DEV void gru_ch(GS& S, f32x4* aR, f32x4* aZ, f32x4* aNH){
  #pragma unroll
  for (int kg = 0; kg < 4; ++kg)
    #pragma unroll
    for (int mt = 0; mt < 2; ++mt){
      bf16x8 a = as_bf(S.a[kg*2+mt]);
      aR[mt]  = mfma16(a, as_bf(S.b[kg*3+0]), aR[mt]);
      aZ[mt]  = mfma16(a, as_bf(S.b[kg*3+1]), aZ[mt]);
      aNH[mt] = mfma16(a, as_bf(S.b[kg*3+2]), aNH[mt]);
    }
}
DEV void gru_cx(GS& S, f32x4* aR, f32x4* aZ, f32x4* aNX){
  #pragma unroll
  for (int kg2 = 0; kg2 < 2; ++kg2)
    #pragma unroll
    for (int mt = 0; mt < 2; ++mt){
      bf16x8 ah, al;
      i32x4 r0 = S.a[(kg2*2+mt)*2], r1 = S.a[(kg2*2+mt)*2+1];
      #pragma unroll
      for (int e = 0; e < 4; ++e){
        float f = __uint_as_float((u32)r0[e]); u32 h = f2bf(f);
        ah[e] = (short)h; al[e] = (short)f2bf(f - bf2f(h));
      }
      #pragma unroll
      for (int e = 0; e < 4; ++e){
        float f = __uint_as_float((u32)r1[e]); u32 h = f2bf(f);
        ah[4+e] = (short)h; al[4+e] = (short)f2bf(f - bf2f(h));
      }
      {
        bf16x8 bh = as_bf(S.b[(0*2+kg2)*3+0]), bl = as_bf(S.b[(1*2+kg2)*3+0]);
        aR[mt] = mfma16(ah, bh, aR[mt]); aR[mt] = mfma16(ah, bl, aR[mt]); aR[mt] = mfma16(al, bh, aR[mt]);
      }
      {
        bf16x8 bh = as_bf(S.b[(0*2+kg2)*3+1]), bl = as_bf(S.b[(1*2+kg2)*3+1]);
        aZ[mt] = mfma16(ah, bh, aZ[mt]); aZ[mt] = mfma16(ah, bl, aZ[mt]); aZ[mt] = mfma16(al, bh, aZ[mt]);
      }
      {
        bf16x8 bh = as_bf(S.b[(0*2+kg2)*3+2]), bl = as_bf(S.b[(1*2+kg2)*3+2]);
        aNX[mt] = mfma16(ah, bh, aNX[mt]); aNX[mt] = mfma16(ah, bl, aNX[mt]); aNX[mt] = mfma16(al, bh, aNX[mt]);
      }
    }
}

__launch_bounds__(128, 1)
__global__ void k_scan(const float* __restrict__ x, char* ws,
                       const float* __restrict__ b_ih, const float* __restrict__ b_hh){
  __shared__ f32x4 mrg[2][4][64];
  const int bid = blockIdx.x;
  const int tid = threadIdx.x;
  const int lane = tid & 63;
  const int w = tid >> 6;
  const int l15 = lane & 15, l4 = lane >> 4;
  const int offA = l15*64 + l4*16;

  if (bid < 128){
    // =============== ESN: group gi (32 batches), panel j (32 cols of R) ===============
    const int gi = bid >> 6, j = bid & 63;
    u32* flgE = (u32*)(ws + OFF_FLG_E) + gi*64;
    const char* Bp = ws + OFF_BE + (size_t)j * 147456u;
    char* hXb = ws + OFF_HX + (size_t)gi * 262144u;
    float* ehf = (float*)(ws + OFF_EHF);

    const char* Bpo  = Bp + w*4096 + offA;                 // h-chunk B base
    const char* pbx0 = Bp + 16*8192 + w*2048 + offA;       // x sub0 B (hi at +0, lo at +4096)
    const char* pbx1 = Bp + 17*8192 + w*2048 + offA;       // x sub1 B
    const char* hbase = hXb + w*4096 + offA;
    const float* xrow = x + (size_t)(gi*32 + l15) * (TT*II) + w*32 + l4*8;

    f32x4 h00 = {0,0,0,0}, h01 = {0,0,0,0}, h10 = {0,0,0,0}, h11 = {0,0,0,0};

    for (int t = 0; t < TT; ++t){
      const char* hAo = hbase + (t & 1) * 131072;
      char* hW = hXb + ((t + 1) & 1) * 131072;
      f32x4 a00 = {0,0,0,0}, a01 = {0,0,0,0}, a10 = {0,0,0,0}, a11 = {0,0,0,0};
      FS S0, S1, S2, S3;
      const float* xb  = xrow + (size_t)t * II;
      const float* xb2 = xb + (size_t)16 * TT * II;

      esn_ix(S0, xb, xb2, pbx0, pbx0 + 4096);
      esn_ix(S1, xb + 64, xb2 + 64, pbx1, pbx1 + 4096);
      if (t) poll_all(flgE + lane, (u32)t);
      else { asm volatile("s_waitcnt vmcnt(0)" ::: "memory"); }
      __builtin_amdgcn_sched_barrier(0);
      esn_cx(S0, a00, a01, a10, a11);
      esn_cx(S1, a00, a01, a10, a11);

      esn_ih(S0, hAo + 0*8192, Bpo + 0*8192);
      esn_ih(S1, hAo + 1*8192, Bpo + 1*8192);
      esn_ih(S2, hAo + 2*8192, Bpo + 2*8192);
      #pragma unroll
      for (int u = 0; u < 16; ++u){
        if (u + 3 < 16){
          const int kn = u + 3;
          if ((u & 3) == 0)      esn_ih(S3, hAo + kn*8192, Bpo + kn*8192);
          else if ((u & 3) == 1) esn_ih(S0, hAo + kn*8192, Bpo + kn*8192);
          else if ((u & 3) == 2) esn_ih(S1, hAo + kn*8192, Bpo + kn*8192);
          else                   esn_ih(S2, hAo + kn*8192, Bpo + kn*8192);
        }
        if (u < 13) WAITV(24);
        else if (u == 13) WAITV(16);
        else if (u == 14) WAITV(8);
        else WAITV(0);
        if ((u & 3) == 0)      esn_ch(S0, a00, a01, a10, a11);
        else if ((u & 3) == 1) esn_ch(S1, a00, a01, a10, a11);
        else if ((u & 3) == 2) esn_ch(S2, a00, a01, a10, a11);
        else                   esn_ch(S3, a00, a01, a10, a11);
      }

      if (w){
        mrg[t&1][0][lane] = a00; mrg[t&1][1][lane] = a01;
        mrg[t&1][2][lane] = a10; mrg[t&1][3][lane] = a11;
      }
      __syncthreads();
      if (!w){
        a00 += mrg[t&1][0][lane]; a01 += mrg[t&1][1][lane];
        a10 += mrg[t&1][2][lane]; a11 += mrg[t&1][3][lane];
        #pragma unroll
        for (int mt = 0; mt < 2; ++mt)
          #pragma unroll
          for (int nt = 0; nt < 2; ++nt){
            f32x4& av = mt ? (nt ? a11 : a10) : (nt ? a01 : a00);
            f32x4& hv = mt ? (nt ? h11 : h10) : (nt ? h01 : h00);
            #pragma unroll
            for (int q = 0; q < 4; ++q){
              float cand = fast_tanh(av[q]);
              float hn = 0.7f * hv[q] + 0.3f * cand;
              hv[q] = hn;
              int m = mt*16 + l4*4 + q;
              int ko = nt*16 + l15;
              st2_sc(hW + (size_t)((j*32 + m)*32 + ko) * 2, f2bf(hn));
              if (t == TT - 1) ehf[(size_t)(gi*32 + m) * 2048 + j*32 + ko] = hn;
            }
          }
        asm volatile("s_waitcnt vmcnt(0)" ::: "memory");
        if (lane == 0) st4_sc(flgE + j, (u32)(t + 1));
      }
    }
  } else {
    // =============== GRU: group gi (32 batches), panel jp (32 of H); wave w owns 16 j's ===============
    const int gb = bid - 128;
    const int gi = gb >> 4, jp = gb & 15;
    u32* flgG = (u32*)(ws + OFF_FLG_G) + gi*16;
    const char* Bp = ws + OFF_BG + (size_t)jp * 147456u;
    char* gXb = ws + OFF_GX + (size_t)gi * 65536u;
    float* ghf = (float*)(ws + OFF_GHF);
    const int j = jp*32 + w*16 + l15;
    const float bR  = b_ih[j] + b_hh[j];
    const float bZ  = b_ih[512 + j] + b_hh[512 + j];
    const float bNX = b_ih[1024 + j];
    const float bNH = b_hh[1024 + j];
    const int offB = (w*16 + l15)*64 + l4*16;
    const char* pbx0 = Bp + 4*24576;
    const char* pbx1 = Bp + 5*24576;
    const float* xrow = x + (size_t)(gi*32 + l15) * (TT*II) + l4*8;

    f32x4 hold[2] = {{0,0,0,0},{0,0,0,0}};

    for (int t = 0; t < TT; ++t){
      const char* hA = gXb + (t & 1) * 32768;
      char* hW = gXb + ((t + 1) & 1) * 32768;
      f32x4 aR[2]  = {{0,0,0,0},{0,0,0,0}};
      f32x4 aZ[2]  = {{0,0,0,0},{0,0,0,0}};
      f32x4 aNH[2] = {{0,0,0,0},{0,0,0,0}};
      f32x4 aNX[2] = {{0,0,0,0},{0,0,0,0}};
      GS S0, S1;
      const float* xb  = xrow + (size_t)t * II;
      const float* xb2 = xb + (size_t)16 * TT * II;

      gru_ix(S0, xb, xb2, pbx0, offB);
      gru_ix(S1, xb + 64, xb2 + 64, pbx1, offB);
      if (t) poll_all(flgG + (lane & 15), (u32)t);
      else { asm volatile("s_waitcnt vmcnt(0)" ::: "memory"); }
      __builtin_amdgcn_sched_barrier(0);
      gru_cx(S0, aR, aZ, aNX);
      gru_ih(S0, hA + 0*8192, Bp + 0*24576, offA, offB);
      gru_cx(S1, aR, aZ, aNX);
      gru_ih(S1, hA + 1*8192, Bp + 1*24576, offA, offB);
      #pragma unroll
      for (int u = 0; u < 4; ++u){
        if (u < 3) WAITV(20); else WAITV(0);
        if (u & 1){
          gru_ch(S1, aR, aZ, aNH);
          if (u + 2 < 4) gru_ih(S1, hA + (u+2)*8192, Bp + (size_t)(u+2)*24576, offA, offB);
        } else {
          gru_ch(S0, aR, aZ, aNH);
          if (u + 2 < 4) gru_ih(S0, hA + (u+2)*8192, Bp + (size_t)(u+2)*24576, offA, offB);
        }
      }
      #pragma unroll
      for (int mt = 0; mt < 2; ++mt)
        #pragma unroll
        for (int q = 0; q < 4; ++q){
          float rv = fast_sigm(aR[mt][q] + bR);
          float zv = fast_sigm(aZ[mt][q] + bZ);
          float nv = fast_tanh(aNX[mt][q] + bNX + rv * (aNH[mt][q] + bNH));
          float hn = (1.f - zv) * nv + zv * hold[mt][q];
          hold[mt][q] = hn;
          int m = mt*16 + l4*4 + q;
          st2_sc(hW + (size_t)((jp*32 + m)*32 + w*16 + l15) * 2, f2bf(hn));
          if (t == TT - 1) ghf[(size_t)(gi*32 + m) * 512 + j] = hn;
        }
      asm volatile("s_waitcnt vmcnt(0)" ::: "memory");
      __syncthreads();
      if (tid == 0) st4_sc(flgG + jp, (u32)(t + 1));
    }
  }
}

// ---------------- f32 epilogue kernels ----------------
__global__ void k_proj(char* ws, const float* __restrict__ pW, const float* __restrict__ pb){
  const float* ehf = (const float*)(ws + OFF_EHF);
  float* proj = (float*)(ws + OFF_PROJ);
  __shared__ float arow[2048];
  int b = blockIdx.x >> 3, jg = blockIdx.x & 7;
  for (int k = threadIdx.x; k < 2048; k += 256) arow[k] = ehf[(size_t)b*2048 + k];
  __syncthreads();
  int wv = threadIdx.x >> 6, lane = threadIdx.x & 63;
  for (int jj = 0; jj < 16; ++jj){
    int jq = jg*64 + wv*16 + jj;
    const float* wr = pW + (size_t)jq * 2048;
    float s = 0.f;
    #pragma unroll 4
    for (int u = 0; u < 32; ++u) s = fmaf(arow[lane + 64*u], wr[lane + 64*u], s);
    s = wred(s);
    if (lane == 0) proj[b*512 + jq] = s + pb[jq];
  }
}

__global__ void k_gate(char* ws, const float* __restrict__ gW, const float* __restrict__ gb){
  const float* proj = (const float*)(ws + OFF_PROJ);
  const float* ghf  = (const float*)(ws + OFF_GHF);
  float* comb = (float*)(ws + OFF_COMB);
  __shared__ float pr[512], gr[512];
  int b = blockIdx.x >> 3, jg = blockIdx.x & 7;
  for (int k = threadIdx.x; k < 512; k += 256){ pr[k] = proj[b*512 + k]; gr[k] = ghf[b*512 + k]; }
  __syncthreads();
  int wv = threadIdx.x >> 6, lane = threadIdx.x & 63;
  for (int jj = 0; jj < 16; ++jj){
    int jq = jg*64 + wv*16 + jj;
    const float* wr = gW + (size_t)jq * 1024;
    float s = 0.f;
    #pragma unroll
    for (int u = 0; u < 8; ++u) s = fmaf(pr[lane + 64*u], wr[lane + 64*u], s);
    #pragma unroll
    for (int u = 0; u < 8; ++u) s = fmaf(gr[lane + 64*u], wr[512 + lane + 64*u], s);
    s = wred(s);
    if (lane == 0){
      float g = fast_sigm(s + gb[jq]);
      comb[b*512 + jq] = g * pr[jq] + (1.f - g) * gr[jq];
    }
  }
}

__global__ void k_head1(char* ws, const float* __restrict__ W1, const float* __restrict__ b1){
  const float* comb = (const float*)(ws + OFF_COMB);
  float* hid = (float*)(ws + OFF_HID);
  __shared__ float cr[512];
  int b = blockIdx.x >> 3, jg = blockIdx.x & 7;
  for (int k = threadIdx.x; k < 512; k += 256) cr[k] = comb[b*512 + k];
  __syncthreads();
  int wv = threadIdx.x >> 6, lane = threadIdx.x & 63;
  for (int jj = 0; jj < 16; ++jj){
    int jq = jg*64 + wv*16 + jj;
    const float* wr = W1 + (size_t)jq * 512;
    float s = 0.f;
    #pragma unroll
    for (int u = 0; u < 8; ++u) s = fmaf(cr[lane + 64*u], wr[lane + 64*u], s);
    s = wred(s);
    if (lane == 0) hid[b*512 + jq] = fmaxf(0.f, s + b1[jq]);
  }
}

__global__ void k_head2(char* ws, const float* __restrict__ W2, const float* __restrict__ b2, float* __restrict__ out){
  const float* hid = (const float*)(ws + OFF_HID);
  __shared__ float hr[512];
  int b = blockIdx.x >> 1, jg = blockIdx.x & 1;
  for (int k = threadIdx.x; k < 512; k += 256) hr[k] = hid[b*512 + k];
  __syncthreads();
  int wv = threadIdx.x >> 6, lane = threadIdx.x & 63;
  for (int jj = 0; jj < 16; ++jj){
    int jq = jg*64 + wv*16 + jj;
    const float* wr = W2 + (size_t)jq * 512;
    float s = 0.f;
    #pragma unroll
    for (int u = 0; u < 8; ++u) s = fmaf(hr[lane + 64*u], wr[lane + 64*u], s);
    s = wred(s);
    if (lane == 0) out[b*128 + jq] = s + b2[jq];
  }
}

// ---------------- launch ----------------
extern "C" void kernel_launch(void* const* d_in, const int* in_sizes, int n_in,
                              void* d_out, int out_size, void* d_ws, size_t ws_size,
                              hipStream_t stream){
  const float* x    = (const float*)d_in[0];
  const float* Win  = (const float*)d_in[1];
  const float* Wres = (const float*)d_in[2];
  const float* Wih  = (const float*)d_in[3];
  const float* Whh  = (const float*)d_in[4];
  const float* bih  = (const float*)d_in[5];
  const float* bhh  = (const float*)d_in[6];
  const float* pW   = (const float*)d_in[7];
  const float* pb   = (const float*)d_in[8];
  const float* gW   = (const float*)d_in[9];
  const float* gb   = (const float*)d_in[10];
  const float* W1   = (const float*)d_in[11];
  const float* b1   = (const float*)d_in[12];
  const float* W2   = (const float*)d_in[13];
  const float* b2   = (const float*)d_in[14];
  char* ws = (char*)d_ws;
  float* out = (float*)d_out;

  k_init<<<dim3(336), dim3(256), 0, stream>>>(ws);
  k_prep<<<dim3(8192), dim3(256), 0, stream>>>(Win, Wres, Wih, Whh, ws);
  k_scan<<<dim3(160), dim3(128), 0, stream>>>(x, ws, bih, bhh);
  k_proj<<<dim3(512), dim3(256), 0, stream>>>(ws, pW, pb);
  k_gate<<<dim3(512), dim3(256), 0, stream>>>(ws, gW, gb);
  k_head1<<<dim3(512), dim3(256), 0, stream>>>(ws, W1, b1);
  k_head2<<<dim3(128), dim3(256), 0, stream>>>(ws, W2, b2, out);
}

// Round 4
// 4843.473 us; speedup vs baseline: 1.3164x; 1.0975x over previous
//
#include <hip/hip_runtime.h>
#include <cstdint>
#include <cstddef>

typedef unsigned int u32;
typedef float  f32x4  __attribute__((ext_vector_type(4)));
typedef int    i32x4  __attribute__((ext_vector_type(4)));
typedef short  bf16x8 __attribute__((ext_vector_type(8)));

#define DEV static __device__ __forceinline__

#define TT 512
#define II 128

// ---------------- workspace layout (bytes) ----------------
#define OFF_FLG_E 0u
#define OFF_FLG_G 8192u
#define OFF_HX    16384u                    // 2 groups * 2 parity * 131072
#define OFF_GX    (OFF_HX + 524288u)        // 2 * 2 * 32768
#define OFF_BE    (OFF_GX + 131072u)        // 64 panels * 18 chunks * 8192
#define OFF_BG    (OFF_BE + 9437184u)       // 16 panels * 6 chunks * 24576
#define OFF_EHF   (OFF_BG + 2359296u)       // 64*2048*4
#define OFF_GHF   (OFF_EHF + 524288u)       // 64*512*4
#define OFF_PROJ  (OFF_GHF + 131072u)
#define OFF_COMB  (OFF_PROJ + 131072u)
#define OFF_HID   (OFF_COMB + 131072u)

// ---------------- small helpers ----------------
DEV u32 f2bf(float f){ u32 u = __float_as_uint(f); return (u + 0x7FFFu + ((u >> 16) & 1u)) >> 16; }
DEV float bf2f(u32 s){ return __uint_as_float(s << 16); }

DEV i32x4 ld4_sc(const void* p){ i32x4 r; asm volatile("global_load_dwordx4 %0, %1, off sc0 sc1" : "=v"(r) : "v"(p)); return r; }
DEV i32x4 ld4(const void* p){ i32x4 r; asm volatile("global_load_dwordx4 %0, %1, off" : "=v"(r) : "v"(p)); return r; }
template<int OFF> DEV i32x4 ld4o(const void* p){ i32x4 r; asm volatile("global_load_dwordx4 %0, %1, off offset:%c2" : "=v"(r) : "v"(p), "n"(OFF)); return r; }
template<int OFF> DEV i32x4 ld4o_sc(const void* p){ i32x4 r; asm volatile("global_load_dwordx4 %0, %1, off offset:%c2 sc0 sc1" : "=v"(r) : "v"(p), "n"(OFF)); return r; }
DEV void st2_sc(void* p, u32 v){ asm volatile("global_store_short %0, %1, off sc0 sc1" :: "v"(p), "v"(v)); }
DEV void st4_sc(void* p, u32 v){ asm volatile("global_store_dword %0, %1, off sc0 sc1" :: "v"(p), "v"(v)); }
// non-blocking flag load: retired by a later counted WAITV
DEV u32 ldflag(const u32* p){ u32 r; asm volatile("global_load_dword %0, %1, off sc0 sc1" : "=v"(r) : "v"(p)); return r; }

#define WAITV(n) do { asm volatile("s_waitcnt vmcnt(" #n ")" ::: "memory"); __builtin_amdgcn_sched_barrier(0); } while(0)

// blocking poll (drains vmcnt): used for pre-poll and the rare stale-flag slow path
DEV void poll_all(const u32* p, u32 tgt){
  for (int it = 0; it < (1 << 22); ++it){
    u32 v;
    asm volatile("global_load_dword %0, %1, off sc0 sc1\n\ts_waitcnt vmcnt(0)" : "=v"(v) : "v"(p) : "memory");
    if (__all((int)(v >= tgt))) return;
    __builtin_amdgcn_s_sleep(1);
  }
}

DEV f32x4 mfma16(bf16x8 a, bf16x8 b, f32x4 c){ return __builtin_amdgcn_mfma_f32_16x16x32_bf16(a, b, c, 0, 0, 0); }
DEV bf16x8 as_bf(i32x4 v){ union { i32x4 i; bf16x8 h; } u; u.i = v; return u.h; }

DEV float fast_tanh(float z){
  z = fminf(15.f, fmaxf(-15.f, z));
  float e = __expf(2.f * z);
  return (e - 1.f) / (e + 1.f);
}
DEV float fast_sigm(float z){
  z = fminf(30.f, fmaxf(-30.f, z));
  return 1.f / (1.f + __expf(-z));
}

DEV float wred(float v){
  #pragma unroll
  for (int o = 32; o > 0; o >>= 1) v += __shfl_xor(v, o, 64);
  return v;
}

// ---------------- init: zero flags + h parity-0 buffers ----------------
__global__ void k_init(char* ws){
  const u32 n0 = 4096, n1 = 32768, n2 = 32768, n3 = 8192, n4 = 8192; // words
  const u32 tot = n0 + n1 + n2 + n3 + n4;
  u32 idx = blockIdx.x * blockDim.x + threadIdx.x;
  u32 stride = gridDim.x * blockDim.x;
  for (u32 k = idx; k < tot; k += stride){
    u32 r = k; u32 off;
    if (r < n0) off = r * 4u;
    else { r -= n0;
      if (r < n1) off = OFF_HX + r * 4u;
      else { r -= n1;
        if (r < n2) off = OFF_HX + 262144u + r * 4u;
        else { r -= n2;
          if (r < n3) off = OFF_GX + r * 4u;
          else { r -= n3; off = OFF_GX + 65536u + r * 4u; } } } }
    *(u32*)(ws + off) = 0u;
  }
}

// ---------------- prep: build packed bf16 B-fragment images (unchanged) ----------------
__global__ void k_prep(const float* __restrict__ Win, const float* __restrict__ Wres,
                       const float* __restrict__ Wih, const float* __restrict__ Whh, char* ws){
  const u32 NE = 64u * 18u * 4096u;   // 4718592
  const u32 NG = 16u * 6u * 12288u;   // 1179648
  u32 idx0 = blockIdx.x * blockDim.x + threadIdx.x;
  u32 stride = gridDim.x * blockDim.x;
  for (u32 idx = idx0; idx < NE + NG; idx += stride){
    if (idx < NE){
      u32 j = idx / 73728u, r = idx % 73728u;
      u32 c = r / 4096u,    e = r % 4096u;
      u32 kg = e >> 10, col = (e >> 5) & 31u, ko = e & 31u;
      u32 gcol = j * 32u + col;
      u32 out = OFF_BE + j * 147456u + c * 8192u + e * 2u;
      u32 val;
      if (c < 16u){
        u32 k = c * 128u + kg * 32u + ko;
        val = f2bf(Wres[k * 2048u + gcol]);
      } else {
        u32 sub = c - 16u, sel = kg >> 1, kg2 = kg & 1u;
        u32 k = sub * 64u + kg2 * 32u + ko;
        float wv = Win[k * 2048u + gcol];
        u32 hi = f2bf(wv);
        val = sel ? f2bf(wv - bf2f(hi)) : hi;
      }
      *(unsigned short*)(ws + out) = (unsigned short)val;
    } else {
      u32 id = idx - NE;
      u32 j = id / 73728u, r = id % 73728u;
      u32 c = r / 12288u,  e = r % 12288u;
      u32 kg = e / 3072u, col = (e >> 5) % 96u, ko = e & 31u;
      u32 gate = col >> 5, jj = col & 31u;
      u32 g = gate * 512u + j * 32u + jj;
      u32 out = OFF_BG + j * 147456u + c * 24576u + e * 2u;
      u32 val;
      if (c < 4u){
        u32 k = c * 128u + kg * 32u + ko;
        val = f2bf(Whh[g * 512u + k]);
      } else {
        u32 sub = c - 4u, sel = kg >> 1, kg2 = kg & 1u;
        u32 k = sub * 64u + kg2 * 32u + ko;
        float wv = Wih[g * 128u + k];
        u32 hi = f2bf(wv);
        val = sel ? f2bf(wv - bf2f(hi)) : hi;
      }
      *(unsigned short*)(ws + out) = (unsigned short)val;
    }
  }
}

// ---------------- scan kernel ----------------
struct FS { i32x4 a0,a1,a2,a3,b0,b1,b2,b3; };
struct GS { i32x4 a[8]; i32x4 b[12]; };

DEV void esn_ih(FS& S, const char* pa, const char* pb){
  S.a0 = ld4o_sc<0>(pa);    S.a1 = ld4o_sc<1024>(pa);
  S.a2 = ld4o_sc<2048>(pa); S.a3 = ld4o_sc<3072>(pa);
  S.b0 = ld4o<0>(pb);       S.b1 = ld4o<1024>(pb);
  S.b2 = ld4o<2048>(pb);    S.b3 = ld4o<3072>(pb);
}
DEV void esn_ix(FS& S, const float* xb, const float* xb2, const char* ph, const char* pl){
  S.a0 = ld4o<0>(xb);  S.a1 = ld4o<16>(xb);
  S.a2 = ld4o<0>(xb2); S.a3 = ld4o<16>(xb2);
  S.b0 = ld4o<0>(ph);  S.b1 = ld4o<1024>(ph);
  S.b2 = ld4o<0>(pl);  S.b3 = ld4o<1024>(pl);
}
DEV void esn_ch(FS& S, f32x4& a00, f32x4& a01, f32x4& a10, f32x4& a11){
  a00 = mfma16(as_bf(S.a0), as_bf(S.b0), a00);
  a01 = mfma16(as_bf(S.a0), as_bf(S.b1), a01);
  a10 = mfma16(as_bf(S.a1), as_bf(S.b0), a10);
  a11 = mfma16(as_bf(S.a1), as_bf(S.b1), a11);
  a00 = mfma16(as_bf(S.a2), as_bf(S.b2), a00);
  a01 = mfma16(as_bf(S.a2), as_bf(S.b3), a01);
  a10 = mfma16(as_bf(S.a3), as_bf(S.b2), a10);
  a11 = mfma16(as_bf(S.a3), as_bf(S.b3), a11);
}
DEV void esn_cx(FS& S, f32x4& a00, f32x4& a01, f32x4& a10, f32x4& a11){
  bf16x8 ah, al, ah2, al2;
  #pragma unroll
  for (int e = 0; e < 4; ++e){
    float f = __uint_as_float((u32)S.a0[e]); u32 h = f2bf(f);
    ah[e] = (short)h; al[e] = (short)f2bf(f - bf2f(h));
  }
  #pragma unroll
  for (int e = 0; e < 4; ++e){
    float f = __uint_as_float((u32)S.a1[e]); u32 h = f2bf(f);
    ah[4+e] = (short)h; al[4+e] = (short)f2bf(f - bf2f(h));
  }
  #pragma unroll
  for (int e = 0; e < 4; ++e){
    float f = __uint_as_float((u32)S.a2[e]); u32 h = f2bf(f);
    ah2[e] = (short)h; al2[e] = (short)f2bf(f - bf2f(h));
  }
  #pragma unroll
  for (int e = 0; e < 4; ++e){
    float f = __uint_as_float((u32)S.a3[e]); u32 h = f2bf(f);
    ah2[4+e] = (short)h; al2[4+e] = (short)f2bf(f - bf2f(h));
  }
  bf16x8 bh0 = as_bf(S.b0), bh1 = as_bf(S.b1), bl0 = as_bf(S.b2), bl1 = as_bf(S.b3);
  a00 = mfma16(ah, bh0, a00);  a00 = mfma16(ah, bl0, a00);  a00 = mfma16(al, bh0, a00);
  a01 = mfma16(ah, bh1, a01);  a01 = mfma16(ah, bl1, a01);  a01 = mfma16(al, bh1, a01);
  a10 = mfma16(ah2, bh0, a10); a10 = mfma16(ah2, bl0, a10); a10 = mfma16(al2, bh0, a10);
  a11 = mfma16(ah2, bh1, a11); a11 = mfma16(ah2, bl1, a11); a11 = mfma16(al2, bh1, a11);
}

DEV void gru_ih(GS& S, const char* pa, const char* pb, int offA, int offB){
  #pragma unroll
  for (int kg = 0; kg < 4; ++kg){
    S.a[kg*2+0] = ld4_sc(pa + kg*2048 + offA);
    S.a[kg*2+1] = ld4_sc(pa + kg*2048 + 1024 + offA);
    #pragma unroll
    for (int g = 0; g < 3; ++g)
      S.b[kg*3+g] = ld4(pb + kg*6144 + g*2048 + offB);
  }
}
DEV void gru_ix(GS& S, const float* xb, const float* xb2, const char* pbx, int offB){
  #pragma unroll
  for (int kg2 = 0; kg2 < 2; ++kg2){
    S.a[(kg2*2+0)*2]   = ld4(xb  + kg2*32);
    S.a[(kg2*2+0)*2+1] = ld4(xb  + kg2*32 + 4);
    S.a[(kg2*2+1)*2]   = ld4(xb2 + kg2*32);
    S.a[(kg2*2+1)*2+1] = ld4(xb2 + kg2*32 + 4);
    #pragma unroll
    for (int sel = 0; sel < 2; ++sel)
      #pragma unroll
      for (int g = 0; g < 3; ++g)
        S.b[(sel*2+kg2)*3+g] = ld4(pbx + (sel*2+kg2)*6144 + g*2048 + offB);
  }
}
DEV void gru_ch(GS& S, f32x4* aR, f32x4* aZ, f32x4* aNH){
  #pragma unroll
  for (int kg = 0; kg < 4; ++kg)
    #pragma unroll
    for (int mt = 0; mt < 2; ++mt){
      bf16x8 a = as_bf(S.a[kg*2+mt]);
      aR[mt]  = mfma16(a, as_bf(S.b[kg*3+0]), aR[mt]);
      aZ[mt]  = mfma16(a, as_bf(S.b[kg*3+1]), aZ[mt]);
      aNH[mt] = mfma16(a, as_bf(S.b[kg*3+2]), aNH[mt]);
    }
}
DEV void gru_cx(GS& S, f32x4* aR, f32x4* aZ, f32x4* aNX){
  #pragma unroll
  for (int kg2 = 0; kg2 < 2; ++kg2)
    #pragma unroll
    for (int mt = 0; mt < 2; ++mt){
      bf16x8 ah, al;
      i32x4 r0 = S.a[(kg2*2+mt)*2], r1 = S.a[(kg2*2+mt)*2+1];
      #pragma unroll
      for (int e = 0; e < 4; ++e){
        float f = __uint_as_float((u32)r0[e]); u32 h = f2bf(f);
        ah[e] = (short)h; al[e] = (short)f2bf(f - bf2f(h));
      }
      #pragma unroll
      for (int e = 0; e < 4; ++e){
        float f = __uint_as_float((u32)r1[e]); u32 h = f2bf(f);
        ah[4+e] = (short)h; al[4+e] = (short)f2bf(f - bf2f(h));
      }
      {
        bf16x8 bh = as_bf(S.b[(0*2+kg2)*3+0]), bl = as_bf(S.b[(1*2+kg2)*3+0]);
        aR[mt] = mfma16(ah, bh, aR[mt]); aR[mt] = mfma16(ah, bl, aR[mt]); aR[mt] = mfma16(al, bh, aR[mt]);
      }
      {
        bf16x8 bh = as_bf(S.b[(0*2+kg2)*3+1]), bl = as_bf(S.b[(1*2+kg2)*3+1]);
        aZ[mt] = mfma16(ah, bh, aZ[mt]); aZ[mt] = mfma16(ah, bl, aZ[mt]); aZ[mt] = mfma16(al, bh, aZ[mt]);
      }
      {
        bf16x8 bh = as_bf(S.b[(0*2+kg2)*3+2]), bl = as_bf(S.b[(1*2+kg2)*3+2]);
        aNX[mt] = mfma16(ah, bh, aNX[mt]); aNX[mt] = mfma16(ah, bl, aNX[mt]); aNX[mt] = mfma16(al, bh, aNX[mt]);
      }
    }
}

__launch_bounds__(128, 1)
__global__ void k_scan(const float* __restrict__ x, char* ws,
                       const float* __restrict__ b_ih, const float* __restrict__ b_hh){
  __shared__ f32x4 mrg[2][4][64];
  const int bid = blockIdx.x;
  const int tid = threadIdx.x;
  const int lane = tid & 63;
  const int w = tid >> 6;
  const int l15 = lane & 15, l4 = lane >> 4;
  const int l3 = lane & 3;
  const int offA = l15*64 + l4*16;

  if (bid < 128){
    // =============== ESN: group gi (32 batches), panel j; JIT dataflow ring over 16 chunks ===============
    const int gi = bid >> 6, j = bid & 63;
    const int cj = j >> 2;                      // own chunk
    u32* flgE = (u32*)(ws + OFF_FLG_E) + gi*64;
    const char* Bp = ws + OFF_BE + (size_t)j * 147456u;
    char* hXb = ws + OFF_HX + (size_t)gi * 262144u;
    float* ehf = (float*)(ws + OFF_EHF);

    const char* Bpo  = Bp + w*4096 + offA;
    const char* pbx0 = Bp + 16*8192 + w*2048 + offA;
    const char* pbx1 = Bp + 17*8192 + w*2048 + offA;
    const char* hbase = hXb + w*4096 + offA;
    const float* xrow = x + (size_t)(gi*32 + l15) * (TT*II) + w*32 + l4*8;

    // fused pre-poll address: 12 flag words for chunks cj+1..cj+3
    const int pm = lane % 12;
    const u32* preE = flgE + 4*((cj + 1 + (pm >> 2)) & 15) + (pm & 3);

    f32x4 h00 = {0,0,0,0}, h01 = {0,0,0,0}, h10 = {0,0,0,0}, h11 = {0,0,0,0};

    for (int t = 0; t < TT; ++t){
      const char* hAo = hbase + (t & 1) * 131072;
      char* hW = hXb + ((t + 1) & 1) * 131072;
      f32x4 a00 = {0,0,0,0}, a01 = {0,0,0,0}, a10 = {0,0,0,0}, a11 = {0,0,0,0};
      FS S0, S1, S2, S3;
      const float* xb  = xrow + (size_t)t * II;
      const float* xb2 = xb + (size_t)16 * TT * II;

      // x loads into S2,S3 (chunk slots 2,3 are free until logical chunks 2,3 are issued)
      esn_ix(S2, xb, xb2, pbx0, pbx0 + 4096);
      esn_ix(S3, xb + 64, xb2 + 64, pbx1, pbx1 + 4096);
      // blocking pre-poll for chunks cj+1..cj+3 (drains the x loads too)
      poll_all(preE, (u32)t);
      __builtin_amdgcn_sched_barrier(0);

      // prologue issue stream: [P3, C0, P4, C1, P5] | x-compute | [C2]
      u32 pvA = ldflag(flgE + 4*((cj+4)&15) + l3);
      { int pc = (cj+1)&15; esn_ih(S0, hAo + pc*8192, Bpo + pc*8192); }
      u32 pvB = ldflag(flgE + 4*((cj+5)&15) + l3);
      { int pc = (cj+2)&15; esn_ih(S1, hAo + pc*8192, Bpo + pc*8192); }
      u32 pvC = ldflag(flgE + 4*((cj+6)&15) + l3);
      esn_cx(S2, a00, a01, a10, a11);
      esn_cx(S3, a00, a01, a10, a11);
      { int pc = (cj+3)&15; esn_ih(S2, hAo + pc*8192, Bpo + pc*8192); }

      // 16 chunk iterations; waits derived from cumulative load positions:
      // u<=10:18, u==11:17, u<=13:16, u==14:8, u==15:0
      #pragma unroll
      for (int u = 0; u < 16; ++u){
        if (u <= 10) WAITV(18);
        else if (u == 11) WAITV(17);
        else if (u <= 13) WAITV(16);
        else if (u == 14) WAITV(8);
        else WAITV(0);
        // check flag for logical chunk u+3 (poll value already retired by the wait)
        if (u <= 12){
          u32 pv = (((u+3)%3)==0) ? pvA : ((((u+3)%3)==1) ? pvB : pvC);
          if (!__all((int)(pv >= (u32)t)))
            poll_all(flgE + 4*((cj+4+u)&15) + l3, (u32)t);   // rare slow path (drains)
        }
        // issue poll for logical chunk u+6
        if (u <= 9){
          const u32* fp = flgE + 4*((cj+7+u)&15) + l3;
          if (((u+3)%3)==0) pvA = ldflag(fp);
          else if (((u+3)%3)==1) pvB = ldflag(fp);
          else pvC = ldflag(fp);
        }
        // issue chunk u+3 into slot (u+3)&3
        if (u <= 12){
          int pc = (cj+4+u)&15;
          const char* pa = hAo + pc*8192; const char* pb = Bpo + pc*8192;
          if (((u+3)&3)==0)      esn_ih(S0, pa, pb);
          else if (((u+3)&3)==1) esn_ih(S1, pa, pb);
          else if (((u+3)&3)==2) esn_ih(S2, pa, pb);
          else                   esn_ih(S3, pa, pb);
        }
        // compute chunk u from slot u&3
        if ((u&3)==0)      esn_ch(S0, a00, a01, a10, a11);
        else if ((u&3)==1) esn_ch(S1, a00, a01, a10, a11);
        else if ((u&3)==2) esn_ch(S2, a00, a01, a10, a11);
        else               esn_ch(S3, a00, a01, a10, a11);
      }

      if (w){
        mrg[t&1][0][lane] = a00; mrg[t&1][1][lane] = a01;
        mrg[t&1][2][lane] = a10; mrg[t&1][3][lane] = a11;
      }
      __syncthreads();
      if (!w){
        a00 += mrg[t&1][0][lane]; a01 += mrg[t&1][1][lane];
        a10 += mrg[t&1][2][lane]; a11 += mrg[t&1][3][lane];
        #pragma unroll
        for (int mt = 0; mt < 2; ++mt)
          #pragma unroll
          for (int nt = 0; nt < 2; ++nt){
            f32x4& av = mt ? (nt ? a11 : a10) : (nt ? a01 : a00);
            f32x4& hv = mt ? (nt ? h11 : h10) : (nt ? h01 : h00);
            #pragma unroll
            for (int q = 0; q < 4; ++q){
              float cand = fast_tanh(av[q]);
              float hn = 0.7f * hv[q] + 0.3f * cand;
              hv[q] = hn;
              int m = mt*16 + l4*4 + q;
              int ko = nt*16 + l15;
              st2_sc(hW + (size_t)((j*32 + m)*32 + ko) * 2, f2bf(hn));
              if (t == TT - 1) ehf[(size_t)(gi*32 + m) * 2048 + j*32 + ko] = hn;
            }
          }
        asm volatile("s_waitcnt vmcnt(0)" ::: "memory");
        if (lane == 0) st4_sc(flgE + j, (u32)(t + 1));
      }
    }
  } else {
    // =============== GRU: group gi, panel jp; JIT ring over 4 chunks ===============
    const int gb = bid - 128;
    const int gi = gb >> 4, jp = gb & 15;
    const int cjg = jp >> 2;                    // own chunk
    u32* flgG = (u32*)(ws + OFF_FLG_G) + gi*16;
    const char* Bp = ws + OFF_BG + (size_t)jp * 147456u;
    char* gXb = ws + OFF_GX + (size_t)gi * 65536u;
    float* ghf = (float*)(ws + OFF_GHF);
    const int j = jp*32 + w*16 + l15;
    const float bR  = b_ih[j] + b_hh[j];
    const float bZ  = b_ih[512 + j] + b_hh[512 + j];
    const float bNX = b_ih[1024 + j];
    const float bNH = b_hh[1024 + j];
    const int offB = (w*16 + l15)*64 + l4*16;
    const char* pbx0 = Bp + 4*24576;
    const char* pbx1 = Bp + 5*24576;
    const float* xrow = x + (size_t)(gi*32 + l15) * (TT*II) + l4*8;

    // fused pre-poll: 8 flag words for chunks cjg+1, cjg+2
    const int pm = lane & 7;
    const u32* preG = flgG + 4*((cjg + 1 + (pm >> 2)) & 3) + (pm & 3);

    f32x4 hold[2] = {{0,0,0,0},{0,0,0,0}};

    for (int t = 0; t < TT; ++t){
      const char* hA = gXb + (t & 1) * 32768;
      char* hW = gXb + ((t + 1) & 1) * 32768;
      f32x4 aR[2]  = {{0,0,0,0},{0,0,0,0}};
      f32x4 aZ[2]  = {{0,0,0,0},{0,0,0,0}};
      f32x4 aNH[2] = {{0,0,0,0},{0,0,0,0}};
      f32x4 aNX[2] = {{0,0,0,0},{0,0,0,0}};
      GS S0, S1;
      const float* xb  = xrow + (size_t)t * II;
      const float* xb2 = xb + (size_t)16 * TT * II;

      gru_ix(S0, xb, xb2, pbx0, offB);
      gru_ix(S1, xb + 64, xb2 + 64, pbx1, offB);
      poll_all(preG, (u32)t);                    // drains x loads
      __builtin_amdgcn_sched_barrier(0);

      // stream: [P(c2)(1)] x-half | [C0(2-21)] [P(c3)(22)] x-half | [C1(23-42)]
      u32 pvA = ldflag(flgG + 4*((cjg+3)&3) + l3);
      gru_cx(S0, aR, aZ, aNX);
      { int pc = (cjg+1)&3; gru_ih(S0, hA + pc*8192, Bp + (size_t)pc*24576, offA, offB); }
      u32 pvB = ldflag(flgG + 4*(cjg&3) + l3);
      gru_cx(S1, aR, aZ, aNX);
      { int pc = (cjg+2)&3; gru_ih(S1, hA + pc*8192, Bp + (size_t)pc*24576, offA, offB); }

      // iter0: need C0(21) & P(c2)(1): T=42 -> WAITV(21)
      WAITV(21);
      if (!__all((int)(pvA >= (u32)t))) poll_all(flgG + 4*((cjg+3)&3) + l3, (u32)t);
      gru_ch(S0, aR, aZ, aNH);
      { int pc = (cjg+3)&3; gru_ih(S0, hA + pc*8192, Bp + (size_t)pc*24576, offA, offB); }
      // iter1: need C1(42) & P(c3)(22): T=62 -> WAITV(20)
      WAITV(20);
      if (!__all((int)(pvB >= (u32)t))) poll_all(flgG + 4*(cjg&3) + l3, (u32)t);
      gru_ch(S1, aR, aZ, aNH);
      { int pc = cjg; gru_ih(S1, hA + pc*8192, Bp + (size_t)pc*24576, offA, offB); }
      // iter2: need C2(62): T=82 -> WAITV(20)
      WAITV(20);
      gru_ch(S0, aR, aZ, aNH);
      // iter3: need C3(82) -> WAITV(0)
      WAITV(0);
      gru_ch(S1, aR, aZ, aNH);

      #pragma unroll
      for (int mt = 0; mt < 2; ++mt)
        #pragma unroll
        for (int q = 0; q < 4; ++q){
          float rv = fast_sigm(aR[mt][q] + bR);
          float zv = fast_sigm(aZ[mt][q] + bZ);
          float nv = fast_tanh(aNX[mt][q] + bNX + rv * (aNH[mt][q] + bNH));
          float hn = (1.f - zv) * nv + zv * hold[mt][q];
          hold[mt][q] = hn;
          int m = mt*16 + l4*4 + q;
          st2_sc(hW + (size_t)((jp*32 + m)*32 + w*16 + l15) * 2, f2bf(hn));
          if (t == TT - 1) ghf[(size_t)(gi*32 + m) * 512 + j] = hn;
        }
      asm volatile("s_waitcnt vmcnt(0)" ::: "memory");
      __syncthreads();
      if (tid == 0) st4_sc(flgG + jp, (u32)(t + 1));
    }
  }
}

// ---------------- f32 epilogue kernels (unchanged) ----------------
__global__ void k_proj(char* ws, const float* __restrict__ pW, const float* __restrict__ pb){
  const float* ehf = (const float*)(ws + OFF_EHF);
  float* proj = (float*)(ws + OFF_PROJ);
  __shared__ float arow[2048];
  int b = blockIdx.x >> 3, jg = blockIdx.x & 7;
  for (int k = threadIdx.x; k < 2048; k += 256) arow[k] = ehf[(size_t)b*2048 + k];
  __syncthreads();
  int wv = threadIdx.x >> 6, lane = threadIdx.x & 63;
  for (int jj = 0; jj < 16; ++jj){
    int jq = jg*64 + wv*16 + jj;
    const float* wr = pW + (size_t)jq * 2048;
    float s = 0.f;
    #pragma unroll 4
    for (int u = 0; u < 32; ++u) s = fmaf(arow[lane + 64*u], wr[lane + 64*u], s);
    s = wred(s);
    if (lane == 0) proj[b*512 + jq] = s + pb[jq];
  }
}

__global__ void k_gate(char* ws, const float* __restrict__ gW, const float* __restrict__ gb){
  const float* proj = (const float*)(ws + OFF_PROJ);
  const float* ghf  = (const float*)(ws + OFF_GHF);
  float* comb = (float*)(ws + OFF_COMB);
  __shared__ float pr[512], gr[512];
  int b = blockIdx.x >> 3, jg = blockIdx.x & 7;
  for (int k = threadIdx.x; k < 512; k += 256){ pr[k] = proj[b*512 + k]; gr[k] = ghf[b*512 + k]; }
  __syncthreads();
  int wv = threadIdx.x >> 6, lane = threadIdx.x & 63;
  for (int jj = 0; jj < 16; ++jj){
    int jq = jg*64 + wv*16 + jj;
    const float* wr = gW + (size_t)jq * 1024;
    float s = 0.f;
    #pragma unroll
    for (int u = 0; u < 8; ++u) s = fmaf(pr[lane + 64*u], wr[lane + 64*u], s);
    #pragma unroll
    for (int u = 0; u < 8; ++u) s = fmaf(gr[lane + 64*u], wr[512 + lane + 64*u], s);
    s = wred(s);
    if (lane == 0){
      float g = fast_sigm(s + gb[jq]);
      comb[b*512 + jq] = g * pr[jq] + (1.f - g) * gr[jq];
    }
  }
}

__global__ void k_head1(char* ws, const float* __restrict__ W1, const float* __restrict__ b1){
  const float* comb = (const float*)(ws + OFF_COMB);
  float* hid = (float*)(ws + OFF_HID);
  __shared__ float cr[512];
  int b = blockIdx.x >> 3, jg = blockIdx.x & 7;
  for (int k = threadIdx.x; k < 512; k += 256) cr[k] = comb[b*512 + k];
  __syncthreads();
  int wv = threadIdx.x >> 6, lane = threadIdx.x & 63;
  for (int jj = 0; jj < 16; ++jj){
    int jq = jg*64 + wv*16 + jj;
    const float* wr = W1 + (size_t)jq * 512;
    float s = 0.f;
    #pragma unroll
    for (int u = 0; u < 8; ++u) s = fmaf(cr[lane + 64*u], wr[lane + 64*u], s);
    s = wred(s);
    if (lane == 0) hid[b*512 + jq] = fmaxf(0.f, s + b1[jq]);
  }
}

__global__ void k_head2(char* ws, const float* __restrict__ W2, const float* __restrict__ b2, float* __restrict__ out){
  const float* hid = (const float*)(ws + OFF_HID);
  __shared__ float hr[512];
  int b = blockIdx.x >> 1, jg = blockIdx.x & 1;
  for (int k = threadIdx.x; k < 512; k += 256) hr[k] = hid[b*512 + k];
  __syncthreads();
  int wv = threadIdx.x >> 6, lane = threadIdx.x & 63;
  for (int jj = 0; jj < 16; ++jj){
    int jq = jg*64 + wv*16 + jj;
    const float* wr = W2 + (size_t)jq * 512;
    float s = 0.f;
    #pragma unroll
    for (int u = 0; u < 8; ++u) s = fmaf(hr[lane + 64*u], wr[lane + 64*u], s);
    s = wred(s);
    if (lane == 0) out[b*128 + jq] = s + b2[jq];
  }
}

// ---------------- launch ----------------
extern "C" void kernel_launch(void* const* d_in, const int* in_sizes, int n_in,
                              void* d_out, int out_size, void* d_ws, size_t ws_size,
                              hipStream_t stream){
  const float* x    = (const float*)d_in[0];
  const float* Win  = (const float*)d_in[1];
  const float* Wres = (const float*)d_in[2];
  const float* Wih  = (const float*)d_in[3];
  const float* Whh  = (const float*)d_in[4];
  const float* bih  = (const float*)d_in[5];
  const float* bhh  = (const float*)d_in[6];
  const float* pW   = (const float*)d_in[7];
  const float* pb   = (const float*)d_in[8];
  const float* gW   = (const float*)d_in[9];
  const float* gb   = (const float*)d_in[10];
  const float* W1   = (const float*)d_in[11];
  const float* b1   = (const float*)d_in[12];
  const float* W2   = (const float*)d_in[13];
  const float* b2   = (const float*)d_in[14];
  char* ws = (char*)d_ws;
  float* out = (float*)d_out;

  k_init<<<dim3(336), dim3(256), 0, stream>>>(ws);
  k_prep<<<dim3(8192), dim3(256), 0, stream>>>(Win, Wres, Wih, Whh, ws);
  k_scan<<<dim3(160), dim3(128), 0, stream>>>(x, ws, bih, bhh);
  k_proj<<<dim3(512), dim3(256), 0, stream>>>(ws, pW, pb);
  k_gate<<<dim3(512), dim3(256), 0, stream>>>(ws, gW, gb);
  k_head1<<<dim3(512), dim3(256), 0, stream>>>(ws, W1, b1);
  k_head2<<<dim3(128), dim3(256), 0, stream>>>(ws, W2, b2, out);
}